// Round 1
// baseline (1868.832 us; speedup 1.0000x reference)
//
#include <hip/hip_runtime.h>

// ---------- types ----------
typedef __bf16 bf16x8 __attribute__((ext_vector_type(8)));
typedef short  s16x8  __attribute__((ext_vector_type(8)));
typedef float  f32x4  __attribute__((ext_vector_type(4)));

union frag_u { s16x8 s; bf16x8 b; };

__device__ __forceinline__ unsigned short f2b(float f) {
  unsigned u = __float_as_uint(f);
  u = (u + 0x7fffu + ((u >> 16) & 1u)) >> 16;   // RNE to bf16
  return (unsigned short)u;
}

// ---------- GEMM: Y[M,128] = bf16(X[M,128]) @ bf16(W[128,128]), fp32 out ----------
// Per block: 128 rows. W staged transposed to LDS as bf16 (row stride 136 -> 16B aligned,
// conflict-free ds_read_b128). A-fragments loaded directly from global (each row read once).
__global__ __launch_bounds__(256) void gemm128(const float* __restrict__ X,
                                               const float* __restrict__ W,
                                               float* __restrict__ Y, int M) {
  __shared__ unsigned short Bs[128 * 136];
  const int tid = threadIdx.x;

  // stage W transposed: Bs[n*136+k] = bf16(W[k*128+n])
#pragma unroll
  for (int i = 0; i < 16; i++) {
    int flat4 = i * 256 + tid;          // 0..4095 float4s
    int k = flat4 >> 5;                 // W row
    int n0 = (flat4 & 31) * 4;          // W col
    float4 v = *(const float4*)(W + k * 128 + n0);
    Bs[(n0 + 0) * 136 + k] = f2b(v.x);
    Bs[(n0 + 1) * 136 + k] = f2b(v.y);
    Bs[(n0 + 2) * 136 + k] = f2b(v.z);
    Bs[(n0 + 3) * 136 + k] = f2b(v.w);
  }
  __syncthreads();

  const int lane = tid & 63;
  const int wave = tid >> 6;
  const int m = lane & 15, q = lane >> 4;
  const int m0 = blockIdx.x * 128;

  const float* xrow[2];
#pragma unroll
  for (int rt = 0; rt < 2; rt++) {
    int r = m0 + (wave * 2 + rt) * 16 + m;
    if (r >= M) r = M - 1;              // tail clamp; stores are guarded
    xrow[rt] = X + (size_t)r * 128;
  }

  f32x4 acc[2][8];
#pragma unroll
  for (int rt = 0; rt < 2; rt++)
#pragma unroll
    for (int ct = 0; ct < 8; ct++) acc[rt][ct] = (f32x4){0.f, 0.f, 0.f, 0.f};

#pragma unroll
  for (int ks = 0; ks < 4; ks++) {
    frag_u a[2];
#pragma unroll
    for (int rt = 0; rt < 2; rt++) {
      const float* p = xrow[rt] + ks * 32 + q * 8;   // A[m][k..k+7], k=ks*32+q*8
      float4 v0 = *(const float4*)p;
      float4 v1 = *(const float4*)(p + 4);
      a[rt].s = (s16x8){(short)f2b(v0.x), (short)f2b(v0.y), (short)f2b(v0.z), (short)f2b(v0.w),
                        (short)f2b(v1.x), (short)f2b(v1.y), (short)f2b(v1.z), (short)f2b(v1.w)};
    }
    frag_u b[8];
#pragma unroll
    for (int ct = 0; ct < 8; ct++) {
      int n = ct * 16 + m;
      b[ct].s = *(const s16x8*)(Bs + n * 136 + ks * 32 + q * 8);
    }
#pragma unroll
    for (int rt = 0; rt < 2; rt++)
#pragma unroll
      for (int ct = 0; ct < 8; ct++)
        acc[rt][ct] = __builtin_amdgcn_mfma_f32_16x16x32_bf16(a[rt].b, b[ct].b, acc[rt][ct], 0, 0, 0);
  }

  // C/D layout: col = lane&15, row = (lane>>4)*4 + reg
#pragma unroll
  for (int rt = 0; rt < 2; rt++) {
#pragma unroll
    for (int i = 0; i < 4; i++) {
      int r = m0 + (wave * 2 + rt) * 16 + q * 4 + i;
      if (r < M) {
        float* yr = Y + (size_t)r * 128 + m;
#pragma unroll
        for (int ct = 0; ct < 8; ct++) yr[ct * 16] = acc[rt][ct][i];
      }
    }
  }
}

// ---------- a[n,h] = sum_c Y[n,h*32+c] * att[h,c] ----------
__global__ __launch_bounds__(256) void head_dot(const float* __restrict__ Y,
                                                const float* __restrict__ att,
                                                float* __restrict__ a, int N) {
  int lane = threadIdx.x & 63;
  int node = blockIdx.x * 4 + (threadIdx.x >> 6);
  if (node >= N) return;
  float2 y = ((const float2*)(Y + (size_t)node * 128))[lane];
  int h = lane >> 4;
  int c0 = (2 * lane) & 31;
  float p = y.x * att[h * 32 + c0] + y.y * att[h * 32 + c0 + 1];
#pragma unroll
  for (int off = 8; off >= 1; off >>= 1) p += __shfl_xor(p, off, 16);
  if ((lane & 15) == 0) a[node * 4 + h] = p;
}

// ---------- GAT pass 1: w[e,h] = exp(leaky(a_s[src]+a_d[dst])); ssum[dst,h] += w ----------
__global__ __launch_bounds__(256) void gat_edge1(const int* __restrict__ ei, int E,
                                                 const float* __restrict__ a_s,
                                                 const float* __restrict__ a_d,
                                                 float* __restrict__ wexp,
                                                 float* __restrict__ ssum) {
  int e = blockIdx.x * 256 + threadIdx.x;
  if (e >= E) return;
  int src = ei[e], dst = ei[E + e];
  float4 as = *(const float4*)(a_s + (size_t)src * 4);
  float4 ad = *(const float4*)(a_d + (size_t)dst * 4);
  float ls[4] = {as.x + ad.x, as.y + ad.y, as.z + ad.z, as.w + ad.w};
#pragma unroll
  for (int h = 0; h < 4; h++) {
    float l = ls[h];
    l = l > 0.f ? l : 0.2f * l;          // leaky_relu(0.2); softmax shift-invariant -> no max pass
    float ex = __expf(l);
    wexp[(size_t)e * 4 + h] = ex;
    atomicAdd(&ssum[(size_t)dst * 4 + h], ex);
  }
}

// ---------- GAT pass 2: out[dst] += scale * (w/(ssum+eps)) * xs[src] ----------
__global__ __launch_bounds__(256) void gat_edge2(const int* __restrict__ ei, int E,
                                                 const float* __restrict__ wexp,
                                                 const float* __restrict__ ssum,
                                                 const float* __restrict__ xs,
                                                 float* __restrict__ out, float scale) {
  long long t = (long long)blockIdx.x * 256 + threadIdx.x;
  int e = (int)(t >> 5);
  if (e >= E) return;
  int g = (int)(t & 31);
  int c4 = g * 4, h = g >> 3;
  int src = ei[e], dst = ei[E + e];
  float alpha = scale * wexp[(size_t)e * 4 + h] / (ssum[(size_t)dst * 4 + h] + 1e-16f);
  float4 x = *(const float4*)(xs + (size_t)src * 128 + c4);
  float* o = out + (size_t)dst * 128 + c4;
  atomicAdd(o + 0, alpha * x.x);
  atomicAdd(o + 1, alpha * x.y);
  atomicAdd(o + 2, alpha * x.z);
  atomicAdd(o + 3, alpha * x.w);
}

// ---------- out[n,c] = x[n,c] + s*bias[c] ----------
__global__ __launch_bounds__(256) void init_bias(const float* __restrict__ x,
                                                 const float* __restrict__ bias,
                                                 float* __restrict__ out, int N, float s) {
  long long t = (long long)blockIdx.x * 256 + threadIdx.x;
  int n = (int)(t >> 5);
  if (n >= N) return;
  int c4 = (int)(t & 31) * 4;
  float4 xv = *(const float4*)(x + (size_t)n * 128 + c4);
  float4 bv = *(const float4*)(bias + c4);
  float4 r = {xv.x + s * bv.x, xv.y + s * bv.y, xv.z + s * bv.z, xv.w + s * bv.w};
  *(float4*)(out + (size_t)n * 128 + c4) = r;
}

// ---------- h_b init: x + s*(h_g*dinv^2 + bias)  (self-loop folded in) ----------
__global__ __launch_bounds__(256) void init_hb(const float* __restrict__ x,
                                               const float* __restrict__ hg,
                                               const float* __restrict__ dinv,
                                               const float* __restrict__ bias,
                                               float* __restrict__ out, int N, float s) {
  long long t = (long long)blockIdx.x * 256 + threadIdx.x;
  int n = (int)(t >> 5);
  if (n >= N) return;
  int c4 = (int)(t & 31) * 4;
  float d = dinv[n], d2 = d * d;
  float4 xv = *(const float4*)(x + (size_t)n * 128 + c4);
  float4 hv = *(const float4*)(hg + (size_t)n * 128 + c4);
  float4 bv = *(const float4*)(bias + c4);
  float4 r = {xv.x + s * (hv.x * d2 + bv.x), xv.y + s * (hv.y * d2 + bv.y),
              xv.z + s * (hv.z * d2 + bv.z), xv.w + s * (hv.w * d2 + bv.w)};
  *(float4*)(out + (size_t)n * 128 + c4) = r;
}

__global__ __launch_bounds__(256) void fill_f32(float* __restrict__ p, int n, float v) {
  int i = blockIdx.x * 256 + threadIdx.x;
  if (i < n) p[i] = v;
}

__global__ __launch_bounds__(256) void deg_count(const int* __restrict__ ei, int E,
                                                 float* __restrict__ deg) {
  int e = blockIdx.x * 256 + threadIdx.x;
  if (e >= E) return;
  atomicAdd(&deg[ei[E + e]], 1.0f);
}

__global__ __launch_bounds__(256) void rsqrt_inplace(float* __restrict__ p, int n) {
  int i = blockIdx.x * 256 + threadIdx.x;
  if (i < n) p[i] = rsqrtf(p[i]);   // deg >= 1 always (self-loop)
}

// ---------- GCN scatter: h_b[dst] += s * dinv[src]*dinv[dst] * h_g[src] ----------
__global__ __launch_bounds__(256) void gcn_scatter(const int* __restrict__ ei, int E,
                                                   const float* __restrict__ hg,
                                                   const float* __restrict__ dinv,
                                                   float* __restrict__ out, float s) {
  long long t = (long long)blockIdx.x * 256 + threadIdx.x;
  int e = (int)(t >> 5);
  if (e >= E) return;
  int c4 = (int)(t & 31) * 4;
  int src = ei[e], dst = ei[E + e];
  float coef = s * dinv[src] * dinv[dst];
  float4 x = *(const float4*)(hg + (size_t)src * 128 + c4);
  float* o = out + (size_t)dst * 128 + c4;
  atomicAdd(o + 0, coef * x.x);
  atomicAdd(o + 1, coef * x.y);
  atomicAdd(o + 2, coef * x.z);
  atomicAdd(o + 3, coef * x.w);
}

extern "C" void kernel_launch(void* const* d_in, const int* in_sizes, int n_in,
                              void* d_out, int out_size, void* d_ws, size_t ws_size,
                              hipStream_t stream) {
  const int Nb = 100000, Nc = 10000, Nt = 1000;
  const int Eb2c = 100000, Ec2t = 10000, Eadj = 800000;

  const float* x_b        = (const float*)d_in[0];
  const float* x_c        = (const float*)d_in[1];
  const float* x_t        = (const float*)d_in[2];
  const int*   e_b2c      = (const int*)d_in[3];
  const int*   e_c2t      = (const int*)d_in[4];
  const int*   e_adj      = (const int*)d_in[5];
  const float* W_b2c_src  = (const float*)d_in[6];
  const float* W_b2c_dst  = (const float*)d_in[7];
  const float* att_b2c_s  = (const float*)d_in[8];
  const float* att_b2c_d  = (const float*)d_in[9];
  const float* b_b2c      = (const float*)d_in[10];
  const float* W_c2t_src  = (const float*)d_in[11];
  const float* W_c2t_dst  = (const float*)d_in[12];
  const float* att_c2t_s  = (const float*)d_in[13];
  const float* att_c2t_d  = (const float*)d_in[14];
  const float* b_c2t      = (const float*)d_in[15];
  const float* W_gcn      = (const float*)d_in[16];
  const float* b_gcn      = (const float*)d_in[17];

  float* h_b = (float*)d_out;
  float* h_c = h_b + (size_t)Nb * 128;
  float* h_t = h_c + (size_t)Nc * 128;

  // xs_b lives in the h_b output region (dead until the GCN stage overwrites it)
  float* xs_b = h_b;

  float* w = (float*)d_ws;
  auto alloc = [&](size_t n) { float* p = w; w += n; return p; };
  float* h_g   = alloc((size_t)Nb * 128);
  float* xd_c  = alloc((size_t)Nc * 128);
  float* xs_c  = alloc((size_t)Nc * 128);
  float* xd_t  = alloc((size_t)Nt * 128);
  float* a_s_b = alloc((size_t)Nb * 4);
  float* a_d_c = alloc((size_t)Nc * 4);
  float* a_s_c = alloc((size_t)Nc * 4);
  float* a_d_t = alloc((size_t)Nt * 4);
  float* w_b2c = alloc((size_t)Eb2c * 4);
  float* w_c2t = alloc((size_t)Ec2t * 4);
  float* s_c   = alloc((size_t)Nc * 4);
  float* s_t   = alloc((size_t)Nt * 4);
  float* deg   = alloc((size_t)Nb);     // becomes dinv in place

#define GB(n) dim3((unsigned)(((long long)(n) + 255) / 256))

  // ---- stage A: building -> cable_group GAT ----
  gemm128<<<(Nb + 127) / 128, 256, 0, stream>>>(x_b, W_b2c_src, xs_b, Nb);
  gemm128<<<(Nc + 127) / 128, 256, 0, stream>>>(x_c, W_b2c_dst, xd_c, Nc);
  gemm128<<<(Nb + 127) / 128, 256, 0, stream>>>(x_b, W_gcn, h_g, Nb);
  head_dot<<<(Nb + 3) / 4, 256, 0, stream>>>(xs_b, att_b2c_s, a_s_b, Nb);
  head_dot<<<(Nc + 3) / 4, 256, 0, stream>>>(xd_c, att_b2c_d, a_d_c, Nc);
  fill_f32<<<GB(Nc * 4), 256, 0, stream>>>(s_c, Nc * 4, 0.f);
  gat_edge1<<<GB(Eb2c), 256, 0, stream>>>(e_b2c, Eb2c, a_s_b, a_d_c, w_b2c, s_c);
  init_bias<<<GB((long long)Nc * 32), 256, 0, stream>>>(x_c, b_b2c, h_c, Nc, 0.5f);
  gat_edge2<<<GB((long long)Eb2c * 32), 256, 0, stream>>>(e_b2c, Eb2c, w_b2c, s_c, xs_b, h_c, 0.5f);

  // ---- stage B: cable_group -> transformer GAT (uses updated h_c) ----
  gemm128<<<(Nc + 127) / 128, 256, 0, stream>>>(h_c, W_c2t_src, xs_c, Nc);
  gemm128<<<(Nt + 127) / 128, 256, 0, stream>>>(x_t, W_c2t_dst, xd_t, Nt);
  head_dot<<<(Nc + 3) / 4, 256, 0, stream>>>(xs_c, att_c2t_s, a_s_c, Nc);
  head_dot<<<(Nt + 3) / 4, 256, 0, stream>>>(xd_t, att_c2t_d, a_d_t, Nt);
  fill_f32<<<GB(Nt * 4), 256, 0, stream>>>(s_t, Nt * 4, 0.f);
  gat_edge1<<<GB(Ec2t), 256, 0, stream>>>(e_c2t, Ec2t, a_s_c, a_d_t, w_c2t, s_t);
  init_bias<<<GB((long long)Nt * 32), 256, 0, stream>>>(x_t, b_c2t, h_t, Nt, 0.5f);
  gat_edge2<<<GB((long long)Ec2t * 32), 256, 0, stream>>>(e_c2t, Ec2t, w_c2t, s_t, xs_c, h_t, 0.5f);

  // ---- GCN on building adjacency ----
  fill_f32<<<GB(Nb), 256, 0, stream>>>(deg, Nb, 1.0f);              // self-loop
  deg_count<<<GB(Eadj), 256, 0, stream>>>(e_adj, Eadj, deg);
  rsqrt_inplace<<<GB(Nb), 256, 0, stream>>>(deg, Nb);               // deg -> dinv
  init_hb<<<GB((long long)Nb * 32), 256, 0, stream>>>(x_b, h_g, deg, b_gcn, h_b, Nb, 0.2f);
  gcn_scatter<<<GB((long long)Eadj * 32), 256, 0, stream>>>(e_adj, Eadj, h_g, deg, h_b, 0.2f);
#undef GB
}

// Round 2
// 685.609 us; speedup vs baseline: 2.7258x; 2.7258x over previous
//
#include <hip/hip_runtime.h>

// ---------- types ----------
typedef __bf16 bf16x8 __attribute__((ext_vector_type(8)));
typedef short  s16x8  __attribute__((ext_vector_type(8)));
typedef float  f32x4  __attribute__((ext_vector_type(4)));

union frag_u { s16x8 s; bf16x8 b; };

__device__ __forceinline__ unsigned short f2b(float f) {
  unsigned u = __float_as_uint(f);
  u = (u + 0x7fffu + ((u >> 16) & 1u)) >> 16;   // RNE to bf16
  return (unsigned short)u;
}

// ---------- GEMM: Y[M,128] = bf16(X[M,128]) @ bf16(W[128,128]), fp32 out ----------
__global__ __launch_bounds__(256) void gemm128(const float* __restrict__ X,
                                               const float* __restrict__ W,
                                               float* __restrict__ Y, int M) {
  __shared__ unsigned short Bs[128 * 136];
  const int tid = threadIdx.x;

  // stage W transposed: Bs[n*136+k] = bf16(W[k*128+n])
#pragma unroll
  for (int i = 0; i < 16; i++) {
    int flat4 = i * 256 + tid;
    int k = flat4 >> 5;
    int n0 = (flat4 & 31) * 4;
    float4 v = *(const float4*)(W + k * 128 + n0);
    Bs[(n0 + 0) * 136 + k] = f2b(v.x);
    Bs[(n0 + 1) * 136 + k] = f2b(v.y);
    Bs[(n0 + 2) * 136 + k] = f2b(v.z);
    Bs[(n0 + 3) * 136 + k] = f2b(v.w);
  }
  __syncthreads();

  const int lane = tid & 63;
  const int wave = tid >> 6;
  const int m = lane & 15, q = lane >> 4;
  const int m0 = blockIdx.x * 128;

  const float* xrow[2];
#pragma unroll
  for (int rt = 0; rt < 2; rt++) {
    int r = m0 + (wave * 2 + rt) * 16 + m;
    if (r >= M) r = M - 1;
    xrow[rt] = X + (size_t)r * 128;
  }

  f32x4 acc[2][8];
#pragma unroll
  for (int rt = 0; rt < 2; rt++)
#pragma unroll
    for (int ct = 0; ct < 8; ct++) acc[rt][ct] = (f32x4){0.f, 0.f, 0.f, 0.f};

#pragma unroll
  for (int ks = 0; ks < 4; ks++) {
    frag_u a[2];
#pragma unroll
    for (int rt = 0; rt < 2; rt++) {
      const float* p = xrow[rt] + ks * 32 + q * 8;
      float4 v0 = *(const float4*)p;
      float4 v1 = *(const float4*)(p + 4);
      a[rt].s = (s16x8){(short)f2b(v0.x), (short)f2b(v0.y), (short)f2b(v0.z), (short)f2b(v0.w),
                        (short)f2b(v1.x), (short)f2b(v1.y), (short)f2b(v1.z), (short)f2b(v1.w)};
    }
    frag_u b[8];
#pragma unroll
    for (int ct = 0; ct < 8; ct++) {
      int n = ct * 16 + m;
      b[ct].s = *(const s16x8*)(Bs + n * 136 + ks * 32 + q * 8);
    }
#pragma unroll
    for (int rt = 0; rt < 2; rt++)
#pragma unroll
      for (int ct = 0; ct < 8; ct++)
        acc[rt][ct] = __builtin_amdgcn_mfma_f32_16x16x32_bf16(a[rt].b, b[ct].b, acc[rt][ct], 0, 0, 0);
  }

  // C/D layout: col = lane&15, row = (lane>>4)*4 + reg
#pragma unroll
  for (int rt = 0; rt < 2; rt++) {
#pragma unroll
    for (int i = 0; i < 4; i++) {
      int r = m0 + (wave * 2 + rt) * 16 + q * 4 + i;
      if (r < M) {
        float* yr = Y + (size_t)r * 128 + m;
#pragma unroll
        for (int ct = 0; ct < 8; ct++) yr[ct * 16] = acc[rt][ct][i];
      }
    }
  }
}

// ---------- a[n,h] = sum_c Y[n,h*32+c] * att[h,c] ----------
__global__ __launch_bounds__(256) void head_dot(const float* __restrict__ Y,
                                                const float* __restrict__ att,
                                                float* __restrict__ a, int N) {
  int lane = threadIdx.x & 63;
  int node = blockIdx.x * 4 + (threadIdx.x >> 6);
  if (node >= N) return;
  float2 y = ((const float2*)(Y + (size_t)node * 128))[lane];
  int h = lane >> 4;
  int c0 = (2 * lane) & 31;
  float p = y.x * att[h * 32 + c0] + y.y * att[h * 32 + c0 + 1];
#pragma unroll
  for (int off = 8; off >= 1; off >>= 1) p += __shfl_xor(p, off, 16);
  if ((lane & 15) == 0) a[node * 4 + h] = p;
}

// ---------- CSR build ----------
__global__ __launch_bounds__(256) void fill_i32(int* __restrict__ p, int n, int v) {
  int i = blockIdx.x * 256 + threadIdx.x;
  if (i < n) p[i] = v;
}

__global__ __launch_bounds__(256) void deg_count_i(const int* __restrict__ ei, int E,
                                                   int* __restrict__ deg) {
  int e = blockIdx.x * 256 + threadIdx.x;
  if (e >= E) return;
  atomicAdd(&deg[ei[E + e]], 1);
}

// single-block exclusive scan: rowptr[0..N] and cursor copy
__global__ __launch_bounds__(1024) void scan_rowptr(const int* __restrict__ deg, int N,
                                                    int* __restrict__ rowptr,
                                                    int* __restrict__ cursor) {
  __shared__ int part[1024];
  int t = threadIdx.x;
  int chunk = (N + 1023) / 1024;
  int lo = t * chunk, hi = min(lo + chunk, N);
  int s = 0;
  for (int i = lo; i < hi; i++) s += deg[i];
  part[t] = s;
  __syncthreads();
  for (int off = 1; off < 1024; off <<= 1) {
    int v = (t >= off) ? part[t - off] : 0;
    __syncthreads();
    part[t] += v;
    __syncthreads();
  }
  int base = (t == 0) ? 0 : part[t - 1];
  for (int i = lo; i < hi; i++) {
    rowptr[i] = base;
    cursor[i] = base;
    base += deg[i];
  }
  if (t == 1023) rowptr[N] = part[1023];
}

__global__ __launch_bounds__(256) void csr_fill(const int* __restrict__ ei, int E,
                                                int* __restrict__ cursor,
                                                int* __restrict__ col) {
  int e = blockIdx.x * 256 + threadIdx.x;
  if (e >= E) return;
  int src = ei[e], dst = ei[E + e];
  int p = atomicAdd(&cursor[dst], 1);
  col[p] = src;
}

__global__ __launch_bounds__(256) void make_dinv(const int* __restrict__ deg,
                                                 float* __restrict__ dinv, int N) {
  int i = blockIdx.x * 256 + threadIdx.x;
  if (i < N) dinv[i] = rsqrtf((float)(deg[i] + 1));   // +1 self-loop
}

// ---------- fused GAT gather: out[d] = xd_in[d] + s*(bias + sum_e w_e xs[src_e] / (sum w + eps)) ----------
// 32 lanes per dst node (4 channels each); softmax-weighted mean in one pass.
__global__ __launch_bounds__(256) void gat_gather(const int* __restrict__ rowptr,
                                                  const int* __restrict__ col,
                                                  const float* __restrict__ a_s,
                                                  const float* __restrict__ a_d,
                                                  const float* __restrict__ xs,
                                                  const float* __restrict__ xd_in,
                                                  const float* __restrict__ bias,
                                                  float* __restrict__ out, int Nd, float s) {
  int node = blockIdx.x * 8 + (threadIdx.x >> 5);
  if (node >= Nd) return;
  int g = threadIdx.x & 31;
  int c4 = g * 4, h = g >> 3;
  int lo = rowptr[node], hi = rowptr[node + 1];
  float ad = a_d[(size_t)node * 4 + h];
  float4 acc = {0.f, 0.f, 0.f, 0.f};
  float sexp = 0.f;
  for (int j = lo; j < hi; j++) {
    int src = col[j];
    float l = a_s[(size_t)src * 4 + h] + ad;
    l = l > 0.f ? l : 0.2f * l;          // leaky_relu(0.2); softmax shift-invariant
    float w = __expf(l);
    sexp += w;
    float4 x = *(const float4*)(xs + (size_t)src * 128 + c4);
    acc.x += w * x.x; acc.y += w * x.y; acc.z += w * x.z; acc.w += w * x.w;
  }
  float inv = s / (sexp + 1e-16f);
  float4 xd = *(const float4*)(xd_in + (size_t)node * 128 + c4);
  float4 bv = *(const float4*)(bias + c4);
  float4 r = {xd.x + s * bv.x + inv * acc.x, xd.y + s * bv.y + inv * acc.y,
              xd.z + s * bv.z + inv * acc.z, xd.w + s * bv.w + inv * acc.w};
  *(float4*)(out + (size_t)node * 128 + c4) = r;
}

// ---------- fused GCN gather: out = x + s*( dinv[d]*sum_e dinv[src] hg[src] + dinv[d]^2 hg[d] + bias ) ----------
__global__ __launch_bounds__(256) void gcn_gather(const int* __restrict__ rowptr,
                                                  const int* __restrict__ col,
                                                  const float* __restrict__ hg,
                                                  const float* __restrict__ dinv,
                                                  const float* __restrict__ x,
                                                  const float* __restrict__ bias,
                                                  float* __restrict__ out, int N, float s) {
  int node = blockIdx.x * 8 + (threadIdx.x >> 5);
  if (node >= N) return;
  int c4 = (threadIdx.x & 31) * 4;
  int lo = rowptr[node], hi = rowptr[node + 1];
  float4 acc = {0.f, 0.f, 0.f, 0.f};
  for (int j = lo; j < hi; j++) {
    int src = col[j];
    float c = dinv[src];
    float4 v = *(const float4*)(hg + (size_t)src * 128 + c4);
    acc.x += c * v.x; acc.y += c * v.y; acc.z += c * v.z; acc.w += c * v.w;
  }
  float dd = dinv[node], d2 = dd * dd;
  float4 self = *(const float4*)(hg + (size_t)node * 128 + c4);
  float4 xv = *(const float4*)(x + (size_t)node * 128 + c4);
  float4 bv = *(const float4*)(bias + c4);
  float4 r = {xv.x + s * (dd * acc.x + d2 * self.x + bv.x),
              xv.y + s * (dd * acc.y + d2 * self.y + bv.y),
              xv.z + s * (dd * acc.z + d2 * self.z + bv.z),
              xv.w + s * (dd * acc.w + d2 * self.w + bv.w)};
  *(float4*)(out + (size_t)node * 128 + c4) = r;
}

extern "C" void kernel_launch(void* const* d_in, const int* in_sizes, int n_in,
                              void* d_out, int out_size, void* d_ws, size_t ws_size,
                              hipStream_t stream) {
  const int Nb = 100000, Nc = 10000, Nt = 1000;
  const int Eb2c = 100000, Ec2t = 10000, Eadj = 800000;

  const float* x_b        = (const float*)d_in[0];
  const float* x_c        = (const float*)d_in[1];
  const float* x_t        = (const float*)d_in[2];
  const int*   e_b2c      = (const int*)d_in[3];
  const int*   e_c2t      = (const int*)d_in[4];
  const int*   e_adj      = (const int*)d_in[5];
  const float* W_b2c_src  = (const float*)d_in[6];
  const float* W_b2c_dst  = (const float*)d_in[7];
  const float* att_b2c_s  = (const float*)d_in[8];
  const float* att_b2c_d  = (const float*)d_in[9];
  const float* b_b2c      = (const float*)d_in[10];
  const float* W_c2t_src  = (const float*)d_in[11];
  const float* W_c2t_dst  = (const float*)d_in[12];
  const float* att_c2t_s  = (const float*)d_in[13];
  const float* att_c2t_d  = (const float*)d_in[14];
  const float* b_c2t      = (const float*)d_in[15];
  const float* W_gcn      = (const float*)d_in[16];
  const float* b_gcn      = (const float*)d_in[17];

  float* h_b = (float*)d_out;
  float* h_c = h_b + (size_t)Nb * 128;
  float* h_t = h_c + (size_t)Nc * 128;

  // xs_b lives in the h_b output region (dead until gcn_gather overwrites it)
  float* xs_b = h_b;

  char* w = (char*)d_ws;
  auto allocf = [&](size_t n) { float* p = (float*)w; w += n * 4; return p; };
  auto alloci = [&](size_t n) { int* p = (int*)w; w += n * 4; return p; };

  float* h_g   = allocf((size_t)Nb * 128);   // 51.2 MB
  float* xd_c  = allocf((size_t)Nc * 128);
  float* xs_c  = allocf((size_t)Nc * 128);
  float* xd_t  = allocf((size_t)Nt * 128);
  float* a_s_b = allocf((size_t)Nb * 4);
  float* a_d_c = allocf((size_t)Nc * 4);
  float* a_s_c = allocf((size_t)Nc * 4);
  float* a_d_t = allocf((size_t)Nt * 4);
  float* dinv  = allocf(Nb);

  int* deg_a  = alloci(Nb);   int* rp_a = alloci(Nb + 1);   int* cur_a = alloci(Nb);
  int* col_a  = alloci(Eadj);
  int* deg_b  = alloci(Nc);   int* rp_b = alloci(Nc + 1);   int* cur_b = alloci(Nc);
  int* col_b  = alloci(Eb2c);
  int* deg_c  = alloci(Nt);   int* rp_c = alloci(Nt + 1);   int* cur_c = alloci(Nt);
  int* col_c  = alloci(Ec2t);

#define GB(n) dim3((unsigned)(((long long)(n) + 255) / 256))

  // ---- CSR builds (front-loaded; independent of GEMMs) ----
  fill_i32<<<GB(Nb), 256, 0, stream>>>(deg_a, Nb, 0);
  fill_i32<<<GB(Nc), 256, 0, stream>>>(deg_b, Nc, 0);
  fill_i32<<<GB(Nt), 256, 0, stream>>>(deg_c, Nt, 0);
  deg_count_i<<<GB(Eadj), 256, 0, stream>>>(e_adj, Eadj, deg_a);
  deg_count_i<<<GB(Eb2c), 256, 0, stream>>>(e_b2c, Eb2c, deg_b);
  deg_count_i<<<GB(Ec2t), 256, 0, stream>>>(e_c2t, Ec2t, deg_c);
  scan_rowptr<<<1, 1024, 0, stream>>>(deg_a, Nb, rp_a, cur_a);
  scan_rowptr<<<1, 1024, 0, stream>>>(deg_b, Nc, rp_b, cur_b);
  scan_rowptr<<<1, 1024, 0, stream>>>(deg_c, Nt, rp_c, cur_c);
  csr_fill<<<GB(Eadj), 256, 0, stream>>>(e_adj, Eadj, cur_a, col_a);
  csr_fill<<<GB(Eb2c), 256, 0, stream>>>(e_b2c, Eb2c, cur_b, col_b);
  csr_fill<<<GB(Ec2t), 256, 0, stream>>>(e_c2t, Ec2t, cur_c, col_c);
  make_dinv<<<GB(Nb), 256, 0, stream>>>(deg_a, dinv, Nb);

  // ---- stage A: building -> cable_group GAT ----
  gemm128<<<(Nb + 127) / 128, 256, 0, stream>>>(x_b, W_b2c_src, xs_b, Nb);
  gemm128<<<(Nc + 127) / 128, 256, 0, stream>>>(x_c, W_b2c_dst, xd_c, Nc);
  gemm128<<<(Nb + 127) / 128, 256, 0, stream>>>(x_b, W_gcn, h_g, Nb);
  head_dot<<<(Nb + 3) / 4, 256, 0, stream>>>(xs_b, att_b2c_s, a_s_b, Nb);
  head_dot<<<(Nc + 3) / 4, 256, 0, stream>>>(xd_c, att_b2c_d, a_d_c, Nc);
  gat_gather<<<(Nc + 7) / 8, 256, 0, stream>>>(rp_b, col_b, a_s_b, a_d_c,
                                               xs_b, x_c, b_b2c, h_c, Nc, 0.5f);

  // ---- stage B: cable_group -> transformer GAT (uses updated h_c) ----
  gemm128<<<(Nc + 127) / 128, 256, 0, stream>>>(h_c, W_c2t_src, xs_c, Nc);
  gemm128<<<(Nt + 127) / 128, 256, 0, stream>>>(x_t, W_c2t_dst, xd_t, Nt);
  head_dot<<<(Nc + 3) / 4, 256, 0, stream>>>(xs_c, att_c2t_s, a_s_c, Nc);
  head_dot<<<(Nt + 3) / 4, 256, 0, stream>>>(xd_t, att_c2t_d, a_d_t, Nt);
  gat_gather<<<(Nt + 7) / 8, 256, 0, stream>>>(rp_c, col_c, a_s_c, a_d_t,
                                               xs_c, x_t, b_c2t, h_t, Nt, 0.5f);

  // ---- GCN on building adjacency (overwrites xs_b region with h_b) ----
  gcn_gather<<<(Nb + 7) / 8, 256, 0, stream>>>(rp_a, col_a, h_g, dinv,
                                               x_b, b_gcn, h_b, Nb, 0.2f);
#undef GB
}

// Round 3
// 480.449 us; speedup vs baseline: 3.8898x; 1.4270x over previous
//
#include <hip/hip_runtime.h>

// ---------- types ----------
typedef __bf16 bf16x8 __attribute__((ext_vector_type(8)));
typedef short  s16x8  __attribute__((ext_vector_type(8)));
typedef float  f32x4  __attribute__((ext_vector_type(4)));

union frag_u { s16x8 s; bf16x8 b; };

__device__ __forceinline__ unsigned short f2b(float f) {
  unsigned u = __float_as_uint(f);
  u = (u + 0x7fffu + ((u >> 16) & 1u)) >> 16;   // RNE to bf16
  return (unsigned short)u;
}

// ---------- GEMM: Y[M,128] = bf16(X[M,128]) @ bf16(W[128,128]), fp32 out ----------
__global__ __launch_bounds__(256) void gemm128(const float* __restrict__ X,
                                               const float* __restrict__ W,
                                               float* __restrict__ Y, int M) {
  __shared__ unsigned short Bs[128 * 136];
  const int tid = threadIdx.x;

  // stage W transposed: Bs[n*136+k] = bf16(W[k*128+n])
#pragma unroll
  for (int i = 0; i < 16; i++) {
    int flat4 = i * 256 + tid;
    int k = flat4 >> 5;
    int n0 = (flat4 & 31) * 4;
    float4 v = *(const float4*)(W + k * 128 + n0);
    Bs[(n0 + 0) * 136 + k] = f2b(v.x);
    Bs[(n0 + 1) * 136 + k] = f2b(v.y);
    Bs[(n0 + 2) * 136 + k] = f2b(v.z);
    Bs[(n0 + 3) * 136 + k] = f2b(v.w);
  }
  __syncthreads();

  const int lane = tid & 63;
  const int wave = tid >> 6;
  const int m = lane & 15, q = lane >> 4;
  const int m0 = blockIdx.x * 128;

  const float* xrow[2];
#pragma unroll
  for (int rt = 0; rt < 2; rt++) {
    int r = m0 + (wave * 2 + rt) * 16 + m;
    if (r >= M) r = M - 1;
    xrow[rt] = X + (size_t)r * 128;
  }

  f32x4 acc[2][8];
#pragma unroll
  for (int rt = 0; rt < 2; rt++)
#pragma unroll
    for (int ct = 0; ct < 8; ct++) acc[rt][ct] = (f32x4){0.f, 0.f, 0.f, 0.f};

#pragma unroll
  for (int ks = 0; ks < 4; ks++) {
    frag_u a[2];
#pragma unroll
    for (int rt = 0; rt < 2; rt++) {
      const float* p = xrow[rt] + ks * 32 + q * 8;
      float4 v0 = *(const float4*)p;
      float4 v1 = *(const float4*)(p + 4);
      a[rt].s = (s16x8){(short)f2b(v0.x), (short)f2b(v0.y), (short)f2b(v0.z), (short)f2b(v0.w),
                        (short)f2b(v1.x), (short)f2b(v1.y), (short)f2b(v1.z), (short)f2b(v1.w)};
    }
    frag_u b[8];
#pragma unroll
    for (int ct = 0; ct < 8; ct++) {
      int n = ct * 16 + m;
      b[ct].s = *(const s16x8*)(Bs + n * 136 + ks * 32 + q * 8);
    }
#pragma unroll
    for (int rt = 0; rt < 2; rt++)
#pragma unroll
      for (int ct = 0; ct < 8; ct++)
        acc[rt][ct] = __builtin_amdgcn_mfma_f32_16x16x32_bf16(a[rt].b, b[ct].b, acc[rt][ct], 0, 0, 0);
  }

  // C/D layout: col = lane&15, row = (lane>>4)*4 + reg
#pragma unroll
  for (int rt = 0; rt < 2; rt++) {
#pragma unroll
    for (int i = 0; i < 4; i++) {
      int r = m0 + (wave * 2 + rt) * 16 + q * 4 + i;
      if (r < M) {
        float* yr = Y + (size_t)r * 128 + m;
#pragma unroll
        for (int ct = 0; ct < 8; ct++) yr[ct * 16] = acc[rt][ct][i];
      }
    }
  }
}

// ---------- a[n,h] = sum_c Y[n,h*32+c] * att[h,c] ----------
__global__ __launch_bounds__(256) void head_dot(const float* __restrict__ Y,
                                                const float* __restrict__ att,
                                                float* __restrict__ a, int N) {
  int lane = threadIdx.x & 63;
  int node = blockIdx.x * 4 + (threadIdx.x >> 6);
  if (node >= N) return;
  float2 y = ((const float2*)(Y + (size_t)node * 128))[lane];
  int h = lane >> 4;
  int c0 = (2 * lane) & 31;
  float p = y.x * att[h * 32 + c0] + y.y * att[h * 32 + c0 + 1];
#pragma unroll
  for (int off = 8; off >= 1; off >>= 1) p += __shfl_xor(p, off, 16);
  if ((lane & 15) == 0) a[node * 4 + h] = p;
}

// ---------- CSR build ----------
__global__ __launch_bounds__(256) void fill_i32(int* __restrict__ p, int n, int v) {
  int i = blockIdx.x * 256 + threadIdx.x;
  if (i < n) p[i] = v;
}

__global__ __launch_bounds__(256) void deg_count_i(const int* __restrict__ ei, int E,
                                                   int* __restrict__ deg) {
  int e = blockIdx.x * 256 + threadIdx.x;
  if (e >= E) return;
  atomicAdd(&deg[ei[E + e]], 1);
}

// ---- hierarchical scan: tile = 2048 elems/block (256 thr x 8) ----
// phase 1: per-block sums
__global__ __launch_bounds__(256) void scan_bsum(const int* __restrict__ deg, int N,
                                                 int* __restrict__ bsum) {
  __shared__ int red[256];
  int t = threadIdx.x;
  int base = blockIdx.x * 2048 + t * 8;
  int s = 0;
  if (base + 8 <= N) {
    int4 a = *(const int4*)(deg + base);
    int4 b = *(const int4*)(deg + base + 4);
    s = a.x + a.y + a.z + a.w + b.x + b.y + b.z + b.w;
  } else {
#pragma unroll
    for (int i = 0; i < 8; i++) { int idx = base + i; if (idx < N) s += deg[idx]; }
  }
  red[t] = s;
  __syncthreads();
  for (int off = 128; off >= 1; off >>= 1) {
    if (t < off) red[t] += red[t + off];
    __syncthreads();
  }
  if (t == 0) bsum[blockIdx.x] = red[0];
}

// phase 2: exclusive scan of block sums (nb <= 256), single block, in place
__global__ __launch_bounds__(256) void scan_bsum_excl(int* __restrict__ bsum, int nb) {
  __shared__ int sh[256];
  int t = threadIdx.x;
  sh[t] = (t < nb) ? bsum[t] : 0;
  __syncthreads();
  for (int off = 1; off < 256; off <<= 1) {
    int v = (t >= off) ? sh[t - off] : 0;
    __syncthreads();
    sh[t] += v;
    __syncthreads();
  }
  if (t < nb) bsum[t] = (t == 0) ? 0 : sh[t - 1];
}

// phase 3: local scan + add-back; writes rowptr[0..N] and cursor[0..N)
__global__ __launch_bounds__(256) void scan_write(const int* __restrict__ deg, int N,
                                                  const int* __restrict__ bsum,
                                                  int* __restrict__ rowptr,
                                                  int* __restrict__ cursor) {
  __shared__ int sh[256];
  int t = threadIdx.x;
  int base = blockIdx.x * 2048 + t * 8;
  int d[8]; int s = 0;
#pragma unroll
  for (int i = 0; i < 8; i++) { int idx = base + i; d[i] = (idx < N) ? deg[idx] : 0; s += d[i]; }
  sh[t] = s;
  __syncthreads();
  for (int off = 1; off < 256; off <<= 1) {
    int v = (t >= off) ? sh[t - off] : 0;
    __syncthreads();
    sh[t] += v;
    __syncthreads();
  }
  int run = bsum[blockIdx.x] + ((t == 0) ? 0 : sh[t - 1]);
#pragma unroll
  for (int i = 0; i < 8; i++) {
    int idx = base + i;
    if (idx < N) {
      rowptr[idx] = run;
      cursor[idx] = run;
      run += d[i];
      if (idx == N - 1) rowptr[N] = run;
    }
  }
}

__global__ __launch_bounds__(256) void csr_fill(const int* __restrict__ ei, int E,
                                                int* __restrict__ cursor,
                                                int* __restrict__ col) {
  int e = blockIdx.x * 256 + threadIdx.x;
  if (e >= E) return;
  int src = ei[e], dst = ei[E + e];
  int p = atomicAdd(&cursor[dst], 1);
  col[p] = src;
}

__global__ __launch_bounds__(256) void make_dinv(const int* __restrict__ deg,
                                                 float* __restrict__ dinv, int N) {
  int i = blockIdx.x * 256 + threadIdx.x;
  if (i < N) dinv[i] = rsqrtf((float)(deg[i] + 1));   // +1 self-loop
}

// ---------- fused GAT gather: out[d] = xd_in[d] + s*(bias + sum_e w_e xs[src_e] / (sum w + eps)) ----------
__global__ __launch_bounds__(256) void gat_gather(const int* __restrict__ rowptr,
                                                  const int* __restrict__ col,
                                                  const float* __restrict__ a_s,
                                                  const float* __restrict__ a_d,
                                                  const float* __restrict__ xs,
                                                  const float* __restrict__ xd_in,
                                                  const float* __restrict__ bias,
                                                  float* __restrict__ out, int Nd, float s) {
  int node = blockIdx.x * 8 + (threadIdx.x >> 5);
  if (node >= Nd) return;
  int g = threadIdx.x & 31;
  int c4 = g * 4, h = g >> 3;
  int lo = rowptr[node], hi = rowptr[node + 1];
  float ad = a_d[(size_t)node * 4 + h];
  float4 acc = {0.f, 0.f, 0.f, 0.f};
  float sexp = 0.f;
  for (int j = lo; j < hi; j++) {
    int src = col[j];
    float l = a_s[(size_t)src * 4 + h] + ad;
    l = l > 0.f ? l : 0.2f * l;          // leaky_relu(0.2); softmax shift-invariant
    float w = __expf(l);
    sexp += w;
    float4 x = *(const float4*)(xs + (size_t)src * 128 + c4);
    acc.x += w * x.x; acc.y += w * x.y; acc.z += w * x.z; acc.w += w * x.w;
  }
  float inv = s / (sexp + 1e-16f);
  float4 xd = *(const float4*)(xd_in + (size_t)node * 128 + c4);
  float4 bv = *(const float4*)(bias + c4);
  float4 r = {xd.x + s * bv.x + inv * acc.x, xd.y + s * bv.y + inv * acc.y,
              xd.z + s * bv.z + inv * acc.z, xd.w + s * bv.w + inv * acc.w};
  *(float4*)(out + (size_t)node * 128 + c4) = r;
}

// ---------- fused GCN gather ----------
__global__ __launch_bounds__(256) void gcn_gather(const int* __restrict__ rowptr,
                                                  const int* __restrict__ col,
                                                  const float* __restrict__ hg,
                                                  const float* __restrict__ dinv,
                                                  const float* __restrict__ x,
                                                  const float* __restrict__ bias,
                                                  float* __restrict__ out, int N, float s) {
  int node = blockIdx.x * 8 + (threadIdx.x >> 5);
  if (node >= N) return;
  int c4 = (threadIdx.x & 31) * 4;
  int lo = rowptr[node], hi = rowptr[node + 1];
  float4 acc = {0.f, 0.f, 0.f, 0.f};
  for (int j = lo; j < hi; j++) {
    int src = col[j];
    float c = dinv[src];
    float4 v = *(const float4*)(hg + (size_t)src * 128 + c4);
    acc.x += c * v.x; acc.y += c * v.y; acc.z += c * v.z; acc.w += c * v.w;
  }
  float dd = dinv[node], d2 = dd * dd;
  float4 self = *(const float4*)(hg + (size_t)node * 128 + c4);
  float4 xv = *(const float4*)(x + (size_t)node * 128 + c4);
  float4 bv = *(const float4*)(bias + c4);
  float4 r = {xv.x + s * (dd * acc.x + d2 * self.x + bv.x),
              xv.y + s * (dd * acc.y + d2 * self.y + bv.y),
              xv.z + s * (dd * acc.z + d2 * self.z + bv.z),
              xv.w + s * (dd * acc.w + d2 * self.w + bv.w)};
  *(float4*)(out + (size_t)node * 128 + c4) = r;
}

extern "C" void kernel_launch(void* const* d_in, const int* in_sizes, int n_in,
                              void* d_out, int out_size, void* d_ws, size_t ws_size,
                              hipStream_t stream) {
  const int Nb = 100000, Nc = 10000, Nt = 1000;
  const int Eb2c = 100000, Ec2t = 10000, Eadj = 800000;

  const float* x_b        = (const float*)d_in[0];
  const float* x_c        = (const float*)d_in[1];
  const float* x_t        = (const float*)d_in[2];
  const int*   e_b2c      = (const int*)d_in[3];
  const int*   e_c2t      = (const int*)d_in[4];
  const int*   e_adj      = (const int*)d_in[5];
  const float* W_b2c_src  = (const float*)d_in[6];
  const float* W_b2c_dst  = (const float*)d_in[7];
  const float* att_b2c_s  = (const float*)d_in[8];
  const float* att_b2c_d  = (const float*)d_in[9];
  const float* b_b2c      = (const float*)d_in[10];
  const float* W_c2t_src  = (const float*)d_in[11];
  const float* W_c2t_dst  = (const float*)d_in[12];
  const float* att_c2t_s  = (const float*)d_in[13];
  const float* att_c2t_d  = (const float*)d_in[14];
  const float* b_c2t      = (const float*)d_in[15];
  const float* W_gcn      = (const float*)d_in[16];
  const float* b_gcn      = (const float*)d_in[17];

  float* h_b = (float*)d_out;
  float* h_c = h_b + (size_t)Nb * 128;
  float* h_t = h_c + (size_t)Nc * 128;

  // xs_b lives in the h_b output region (dead until gcn_gather overwrites it)
  float* xs_b = h_b;

  char* w = (char*)d_ws;
  auto allocf = [&](size_t n) { float* p = (float*)w; w += n * 4; return p; };
  auto alloci = [&](size_t n) { int* p = (int*)w; w += n * 4; return p; };

  float* h_g   = allocf((size_t)Nb * 128);   // 51.2 MB
  float* xd_c  = allocf((size_t)Nc * 128);
  float* xs_c  = allocf((size_t)Nc * 128);
  float* xd_t  = allocf((size_t)Nt * 128);
  float* a_s_b = allocf((size_t)Nb * 4);
  float* a_d_c = allocf((size_t)Nc * 4);
  float* a_s_c = allocf((size_t)Nc * 4);
  float* a_d_t = allocf((size_t)Nt * 4);
  float* dinv  = allocf(Nb);

  int* deg_a  = alloci(Nb);   int* rp_a = alloci(Nb + 1);   int* cur_a = alloci(Nb);
  int* col_a  = alloci(Eadj);
  int* deg_b  = alloci(Nc);   int* rp_b = alloci(Nc + 1);   int* cur_b = alloci(Nc);
  int* col_b  = alloci(Eb2c);
  int* deg_c  = alloci(Nt);   int* rp_c = alloci(Nt + 1);   int* cur_c = alloci(Nt);
  int* col_c  = alloci(Ec2t);
  int* bs_a   = alloci(256);
  int* bs_b   = alloci(256);
  int* bs_c   = alloci(256);

#define GB(n) dim3((unsigned)(((long long)(n) + 255) / 256))
#define SB(n) dim3((unsigned)(((long long)(n) + 2047) / 2048))

  // ---- CSR builds ----
  fill_i32<<<GB(Nb), 256, 0, stream>>>(deg_a, Nb, 0);
  fill_i32<<<GB(Nc), 256, 0, stream>>>(deg_b, Nc, 0);
  fill_i32<<<GB(Nt), 256, 0, stream>>>(deg_c, Nt, 0);
  deg_count_i<<<GB(Eadj), 256, 0, stream>>>(e_adj, Eadj, deg_a);
  deg_count_i<<<GB(Eb2c), 256, 0, stream>>>(e_b2c, Eb2c, deg_b);
  deg_count_i<<<GB(Ec2t), 256, 0, stream>>>(e_c2t, Ec2t, deg_c);

  scan_bsum<<<SB(Nb), 256, 0, stream>>>(deg_a, Nb, bs_a);
  scan_bsum<<<SB(Nc), 256, 0, stream>>>(deg_b, Nc, bs_b);
  scan_bsum<<<SB(Nt), 256, 0, stream>>>(deg_c, Nt, bs_c);
  scan_bsum_excl<<<1, 256, 0, stream>>>(bs_a, (Nb + 2047) / 2048);
  scan_bsum_excl<<<1, 256, 0, stream>>>(bs_b, (Nc + 2047) / 2048);
  scan_bsum_excl<<<1, 256, 0, stream>>>(bs_c, (Nt + 2047) / 2048);
  scan_write<<<SB(Nb), 256, 0, stream>>>(deg_a, Nb, bs_a, rp_a, cur_a);
  scan_write<<<SB(Nc), 256, 0, stream>>>(deg_b, Nc, bs_b, rp_b, cur_b);
  scan_write<<<SB(Nt), 256, 0, stream>>>(deg_c, Nt, bs_c, rp_c, cur_c);

  csr_fill<<<GB(Eadj), 256, 0, stream>>>(e_adj, Eadj, cur_a, col_a);
  csr_fill<<<GB(Eb2c), 256, 0, stream>>>(e_b2c, Eb2c, cur_b, col_b);
  csr_fill<<<GB(Ec2t), 256, 0, stream>>>(e_c2t, Ec2t, cur_c, col_c);
  make_dinv<<<GB(Nb), 256, 0, stream>>>(deg_a, dinv, Nb);

  // ---- stage A: building -> cable_group GAT ----
  gemm128<<<(Nb + 127) / 128, 256, 0, stream>>>(x_b, W_b2c_src, xs_b, Nb);
  gemm128<<<(Nc + 127) / 128, 256, 0, stream>>>(x_c, W_b2c_dst, xd_c, Nc);
  gemm128<<<(Nb + 127) / 128, 256, 0, stream>>>(x_b, W_gcn, h_g, Nb);
  head_dot<<<(Nb + 3) / 4, 256, 0, stream>>>(xs_b, att_b2c_s, a_s_b, Nb);
  head_dot<<<(Nc + 3) / 4, 256, 0, stream>>>(xd_c, att_b2c_d, a_d_c, Nc);
  gat_gather<<<(Nc + 7) / 8, 256, 0, stream>>>(rp_b, col_b, a_s_b, a_d_c,
                                               xs_b, x_c, b_b2c, h_c, Nc, 0.5f);

  // ---- stage B: cable_group -> transformer GAT (uses updated h_c) ----
  gemm128<<<(Nc + 127) / 128, 256, 0, stream>>>(h_c, W_c2t_src, xs_c, Nc);
  gemm128<<<(Nt + 127) / 128, 256, 0, stream>>>(x_t, W_c2t_dst, xd_t, Nt);
  head_dot<<<(Nc + 3) / 4, 256, 0, stream>>>(xs_c, att_c2t_s, a_s_c, Nc);
  head_dot<<<(Nt + 3) / 4, 256, 0, stream>>>(xd_t, att_c2t_d, a_d_t, Nt);
  gat_gather<<<(Nt + 7) / 8, 256, 0, stream>>>(rp_c, col_c, a_s_c, a_d_t,
                                               xs_c, x_t, b_c2t, h_t, Nt, 0.5f);

  // ---- GCN on building adjacency (overwrites xs_b region with h_b) ----
  gcn_gather<<<(Nb + 7) / 8, 256, 0, stream>>>(rp_a, col_a, h_g, dinv,
                                               x_b, b_gcn, h_b, Nb, 0.2f);
#undef GB
#undef SB
}

// Round 4
// 406.189 us; speedup vs baseline: 4.6009x; 1.1828x over previous
//
#include <hip/hip_runtime.h>

#define NB 100000
#define NC 10000
#define NT 1000
#define EADJ 800000
#define EB2C 100000
#define EC2T 10000

// block counts for the merged hierarchical scan (tile = 2048)
#define SBA 49   // ceil(NB/2048)
#define SBB 5    // ceil(NC/2048)
#define SBC 1    // ceil(NT/2048)

// ---------- types ----------
typedef __bf16 bf16x8 __attribute__((ext_vector_type(8)));
typedef short  s16x8  __attribute__((ext_vector_type(8)));
typedef float  f32x4  __attribute__((ext_vector_type(4)));

union frag_u { s16x8 s; bf16x8 b; };

__device__ __forceinline__ unsigned short f2b(float f) {
  unsigned u = __float_as_uint(f);
  u = (u + 0x7fffu + ((u >> 16) & 1u)) >> 16;   // RNE to bf16
  return (unsigned short)u;
}
__device__ __forceinline__ float b2f(unsigned short u) {
  return __uint_as_float(((unsigned)u) << 16);
}

// ================= CSR build (merged across 3 edge sets) =================

__global__ __launch_bounds__(256) void deg_count_all(const int* __restrict__ ea,
                                                     const int* __restrict__ eb,
                                                     const int* __restrict__ ec,
                                                     int* __restrict__ da,
                                                     int* __restrict__ db,
                                                     int* __restrict__ dc) {
  int t = blockIdx.x * 256 + threadIdx.x;
  if (t < EADJ) {
    atomicAdd(&da[ea[EADJ + t]], 1);
  } else if (t < EADJ + EB2C) {
    int e = t - EADJ;
    atomicAdd(&db[eb[EB2C + e]], 1);
  } else if (t < EADJ + EB2C + EC2T) {
    int e = t - EADJ - EB2C;
    atomicAdd(&dc[ec[EC2T + e]], 1);
  }
}

// phase 1: per-block (2048-elem tile) sums
__global__ __launch_bounds__(256) void scan_bsum_all(const int* __restrict__ da,
                                                     const int* __restrict__ db,
                                                     const int* __restrict__ dc,
                                                     int* __restrict__ bs) {
  const int* deg; int N, lb; int* out;
  int b = blockIdx.x;
  if (b < SBA)            { deg = da; N = NB; lb = b;            out = bs; }
  else if (b < SBA + SBB) { deg = db; N = NC; lb = b - SBA;      out = bs + SBA; }
  else                    { deg = dc; N = NT; lb = 0;            out = bs + SBA + SBB; }
  __shared__ int red[256];
  int t = threadIdx.x;
  int base = lb * 2048 + t * 8;
  int s = 0;
  if (base + 8 <= N) {
    int4 a = *(const int4*)(deg + base);
    int4 c = *(const int4*)(deg + base + 4);
    s = a.x + a.y + a.z + a.w + c.x + c.y + c.z + c.w;
  } else {
#pragma unroll
    for (int i = 0; i < 8; i++) { int idx = base + i; if (idx < N) s += deg[idx]; }
  }
  red[t] = s;
  __syncthreads();
  for (int off = 128; off >= 1; off >>= 1) {
    if (t < off) red[t] += red[t + off];
    __syncthreads();
  }
  if (t == 0) out[lb] = red[0];
}

// phase 2: exclusive scans of the 3 block-sum segments (3 blocks)
__global__ __launch_bounds__(256) void scan_excl_all(int* __restrict__ bs) {
  int* p; int n;
  if (blockIdx.x == 0)      { p = bs;             n = SBA; }
  else if (blockIdx.x == 1) { p = bs + SBA;       n = SBB; }
  else                      { p = bs + SBA + SBB; n = SBC; }
  __shared__ int sh[256];
  int t = threadIdx.x;
  sh[t] = (t < n) ? p[t] : 0;
  __syncthreads();
  for (int off = 1; off < 256; off <<= 1) {
    int v = (t >= off) ? sh[t - off] : 0;
    __syncthreads();
    sh[t] += v;
    __syncthreads();
  }
  if (t < n) p[t] = (t == 0) ? 0 : sh[t - 1];
}

// phase 3: local scan + add-back -> rowptr/cursor; set-a also writes dinv
__global__ __launch_bounds__(256) void scan_write_all(const int* __restrict__ da,
                                                      const int* __restrict__ db,
                                                      const int* __restrict__ dc,
                                                      const int* __restrict__ bs,
                                                      int* __restrict__ rp_a, int* __restrict__ cur_a,
                                                      int* __restrict__ rp_b, int* __restrict__ cur_b,
                                                      int* __restrict__ rp_c, int* __restrict__ cur_c,
                                                      float* __restrict__ dinv) {
  const int* deg; int N, lb; const int* bsum; int* rp; int* cur; bool dodinv = false;
  int b = blockIdx.x;
  if (b < SBA)            { deg = da; N = NB; lb = b;       bsum = bs;             rp = rp_a; cur = cur_a; dodinv = true; }
  else if (b < SBA + SBB) { deg = db; N = NC; lb = b - SBA; bsum = bs + SBA;       rp = rp_b; cur = cur_b; }
  else                    { deg = dc; N = NT; lb = 0;       bsum = bs + SBA + SBB; rp = rp_c; cur = cur_c; }
  __shared__ int sh[256];
  int t = threadIdx.x;
  int base = lb * 2048 + t * 8;
  int d[8]; int s = 0;
#pragma unroll
  for (int i = 0; i < 8; i++) { int idx = base + i; d[i] = (idx < N) ? deg[idx] : 0; s += d[i]; }
  sh[t] = s;
  __syncthreads();
  for (int off = 1; off < 256; off <<= 1) {
    int v = (t >= off) ? sh[t - off] : 0;
    __syncthreads();
    sh[t] += v;
    __syncthreads();
  }
  int run = bsum[lb] + ((t == 0) ? 0 : sh[t - 1]);
#pragma unroll
  for (int i = 0; i < 8; i++) {
    int idx = base + i;
    if (idx < N) {
      rp[idx] = run;
      cur[idx] = run;
      run += d[i];
      if (idx == N - 1) rp[N] = run;
      if (dodinv) dinv[idx] = rsqrtf((float)(d[i] + 1));   // +1 self-loop
    }
  }
}

__global__ __launch_bounds__(256) void csr_fill_all(const int* __restrict__ ea,
                                                    const int* __restrict__ eb,
                                                    const int* __restrict__ ec,
                                                    int* __restrict__ cur_a, int* __restrict__ cur_b, int* __restrict__ cur_c,
                                                    int* __restrict__ col_a, int* __restrict__ col_b, int* __restrict__ col_c) {
  int t = blockIdx.x * 256 + threadIdx.x;
  if (t < EADJ) {
    int src = ea[t], dst = ea[EADJ + t];
    col_a[atomicAdd(&cur_a[dst], 1)] = src;
  } else if (t < EADJ + EB2C) {
    int e = t - EADJ;
    int src = eb[e], dst = eb[EB2C + e];
    col_b[atomicAdd(&cur_b[dst], 1)] = src;
  } else if (t < EADJ + EB2C + EC2T) {
    int e = t - EADJ - EB2C;
    int src = ec[e], dst = ec[EC2T + e];
    col_c[atomicAdd(&cur_c[dst], 1)] = src;
  }
}

// ================= attention-weight folding =================
// wt[mat][k*4+h] = sum_c W[k, h*32+c] * att[h,c]   (4 matrices, one block)
__global__ __launch_bounds__(256) void prep_watt(const float* __restrict__ W0, const float* __restrict__ A0,
                                                 const float* __restrict__ W1, const float* __restrict__ A1,
                                                 const float* __restrict__ W2, const float* __restrict__ A2,
                                                 const float* __restrict__ W3, const float* __restrict__ A3,
                                                 float* __restrict__ wt) {
  const float* Ws[4] = {W0, W1, W2, W3};
  const float* As[4] = {A0, A1, A2, A3};
  int t = threadIdx.x;
#pragma unroll
  for (int mm = 0; mm < 4; mm++) {
#pragma unroll
    for (int r = 0; r < 2; r++) {
      int idx = r * 256 + t;           // 0..511 over (k,h)
      int k = idx >> 2, h = idx & 3;
      float s = 0.f;
      for (int c = 0; c < 32; c++) s += Ws[mm][k * 128 + h * 32 + c] * As[mm][h * 32 + c];
      wt[mm * 512 + k * 4 + h] = s;
    }
  }
}

// a_d for cable (wt+512) and transformer (wt+1536) nodes: one wave per node
__global__ __launch_bounds__(256) void small_ad(const float* __restrict__ x_c,
                                                const float* __restrict__ x_t,
                                                const float* __restrict__ wt,
                                                float* __restrict__ a_d_c,
                                                float* __restrict__ a_d_t) {
  int widx = blockIdx.x * 4 + (threadIdx.x >> 6);
  int lane = threadIdx.x & 63;
  const float* x; const float* w; float* out;
  if (widx < NC)            { x = x_c + (size_t)widx * 128;        w = wt + 512;  out = a_d_c + widx * 4; }
  else if (widx < NC + NT)  { int n = widx - NC; x = x_t + (size_t)n * 128; w = wt + 1536; out = a_d_t + n * 4; }
  else return;
  float2 xv = ((const float2*)x)[lane];
  float p[4];
#pragma unroll
  for (int h = 0; h < 4; h++)
    p[h] = xv.x * w[(2 * lane) * 4 + h] + xv.y * w[(2 * lane + 1) * 4 + h];
#pragma unroll
  for (int off = 32; off >= 1; off >>= 1)
#pragma unroll
    for (int h = 0; h < 4; h++) p[h] += __shfl_xor(p[h], off);
  if (lane == 0) *(float4*)out = (float4){p[0], p[1], p[2], p[3]};
}

// ================= fused GEMMs =================
// gemm_dual: xs_out = bf16(X@W1), hg_out = bf16(dinv[r] * (X@W2)), as_out = (X@W1)·att_src via w̃ MFMA tile
__global__ __launch_bounds__(256) void gemm_dual(const float* __restrict__ X,
                                                 const float* __restrict__ W1,
                                                 const float* __restrict__ W2,
                                                 const float* __restrict__ wt,    // [128*4]
                                                 const float* __restrict__ dinv,
                                                 unsigned short* __restrict__ xs_out,
                                                 unsigned short* __restrict__ hg_out,
                                                 float* __restrict__ as_out, int M) {
  __shared__ unsigned short Bs1[128 * 136];
  __shared__ unsigned short Bs2[128 * 136];
  __shared__ unsigned short Wsh[16 * 136];
  const int tid = threadIdx.x;

#pragma unroll
  for (int i = 0; i < 16; i++) {
    int flat4 = i * 256 + tid;
    int k = flat4 >> 5;
    int n0 = (flat4 & 31) * 4;
    float4 v1 = *(const float4*)(W1 + k * 128 + n0);
    float4 v2 = *(const float4*)(W2 + k * 128 + n0);
    Bs1[(n0 + 0) * 136 + k] = f2b(v1.x);
    Bs1[(n0 + 1) * 136 + k] = f2b(v1.y);
    Bs1[(n0 + 2) * 136 + k] = f2b(v1.z);
    Bs1[(n0 + 3) * 136 + k] = f2b(v1.w);
    Bs2[(n0 + 0) * 136 + k] = f2b(v2.x);
    Bs2[(n0 + 1) * 136 + k] = f2b(v2.y);
    Bs2[(n0 + 2) * 136 + k] = f2b(v2.z);
    Bs2[(n0 + 3) * 136 + k] = f2b(v2.w);
  }
#pragma unroll
  for (int r = 0; r < 8; r++) {
    int idx = r * 256 + tid;           // 0..2047 over (n,k)
    int n = idx >> 7, k = idx & 127;
    Wsh[n * 136 + k] = (n < 4) ? f2b(wt[k * 4 + n]) : (unsigned short)0;
  }
  __syncthreads();

  const int lane = tid & 63;
  const int wave = tid >> 6;
  const int m = lane & 15, q = lane >> 4;
  const int m0 = blockIdx.x * 128;

  const float* xrow[2];
#pragma unroll
  for (int rt = 0; rt < 2; rt++) {
    int r = m0 + (wave * 2 + rt) * 16 + m;
    if (r >= M) r = M - 1;
    xrow[rt] = X + (size_t)r * 128;
  }

  f32x4 acc1[2][8], acc2[2][8], accw[2];
#pragma unroll
  for (int rt = 0; rt < 2; rt++) {
    accw[rt] = (f32x4){0.f, 0.f, 0.f, 0.f};
#pragma unroll
    for (int ct = 0; ct < 8; ct++) {
      acc1[rt][ct] = (f32x4){0.f, 0.f, 0.f, 0.f};
      acc2[rt][ct] = (f32x4){0.f, 0.f, 0.f, 0.f};
    }
  }

#pragma unroll
  for (int ks = 0; ks < 4; ks++) {
    frag_u a[2];
#pragma unroll
    for (int rt = 0; rt < 2; rt++) {
      const float* p = xrow[rt] + ks * 32 + q * 8;
      float4 v0 = *(const float4*)p;
      float4 v1 = *(const float4*)(p + 4);
      a[rt].s = (s16x8){(short)f2b(v0.x), (short)f2b(v0.y), (short)f2b(v0.z), (short)f2b(v0.w),
                        (short)f2b(v1.x), (short)f2b(v1.y), (short)f2b(v1.z), (short)f2b(v1.w)};
    }
    frag_u bw;
    bw.s = *(const s16x8*)(Wsh + m * 136 + ks * 32 + q * 8);
#pragma unroll
    for (int rt = 0; rt < 2; rt++)
      accw[rt] = __builtin_amdgcn_mfma_f32_16x16x32_bf16(a[rt].b, bw.b, accw[rt], 0, 0, 0);
#pragma unroll
    for (int ct = 0; ct < 8; ct++) {
      frag_u b1, b2;
      b1.s = *(const s16x8*)(Bs1 + (ct * 16 + m) * 136 + ks * 32 + q * 8);
      b2.s = *(const s16x8*)(Bs2 + (ct * 16 + m) * 136 + ks * 32 + q * 8);
#pragma unroll
      for (int rt = 0; rt < 2; rt++) {
        acc1[rt][ct] = __builtin_amdgcn_mfma_f32_16x16x32_bf16(a[rt].b, b1.b, acc1[rt][ct], 0, 0, 0);
        acc2[rt][ct] = __builtin_amdgcn_mfma_f32_16x16x32_bf16(a[rt].b, b2.b, acc2[rt][ct], 0, 0, 0);
      }
    }
  }

  // C/D layout: col = lane&15 (=m), row = q*4 + reg
#pragma unroll
  for (int rt = 0; rt < 2; rt++) {
#pragma unroll
    for (int i = 0; i < 4; i++) {
      int r = m0 + (wave * 2 + rt) * 16 + q * 4 + i;
      if (r < M) {
        float dd = dinv[r];
        unsigned short* xr = xs_out + (size_t)r * 128 + m;
        unsigned short* hr = hg_out + (size_t)r * 128 + m;
#pragma unroll
        for (int ct = 0; ct < 8; ct++) {
          xr[ct * 16] = f2b(acc1[rt][ct][i]);
          hr[ct * 16] = f2b(dd * acc2[rt][ct][i]);
        }
        if (m < 4) as_out[(size_t)r * 4 + m] = accw[rt][i];
      }
    }
  }
}

// gemm_single: xs_out = bf16(X@W1), as_out via w̃ tile
__global__ __launch_bounds__(256) void gemm_single(const float* __restrict__ X,
                                                   const float* __restrict__ W1,
                                                   const float* __restrict__ wt,
                                                   unsigned short* __restrict__ xs_out,
                                                   float* __restrict__ as_out, int M) {
  __shared__ unsigned short Bs1[128 * 136];
  __shared__ unsigned short Wsh[16 * 136];
  const int tid = threadIdx.x;

#pragma unroll
  for (int i = 0; i < 16; i++) {
    int flat4 = i * 256 + tid;
    int k = flat4 >> 5;
    int n0 = (flat4 & 31) * 4;
    float4 v1 = *(const float4*)(W1 + k * 128 + n0);
    Bs1[(n0 + 0) * 136 + k] = f2b(v1.x);
    Bs1[(n0 + 1) * 136 + k] = f2b(v1.y);
    Bs1[(n0 + 2) * 136 + k] = f2b(v1.z);
    Bs1[(n0 + 3) * 136 + k] = f2b(v1.w);
  }
#pragma unroll
  for (int r = 0; r < 8; r++) {
    int idx = r * 256 + tid;
    int n = idx >> 7, k = idx & 127;
    Wsh[n * 136 + k] = (n < 4) ? f2b(wt[k * 4 + n]) : (unsigned short)0;
  }
  __syncthreads();

  const int lane = tid & 63;
  const int wave = tid >> 6;
  const int m = lane & 15, q = lane >> 4;
  const int m0 = blockIdx.x * 128;

  const float* xrow[2];
#pragma unroll
  for (int rt = 0; rt < 2; rt++) {
    int r = m0 + (wave * 2 + rt) * 16 + m;
    if (r >= M) r = M - 1;
    xrow[rt] = X + (size_t)r * 128;
  }

  f32x4 acc1[2][8], accw[2];
#pragma unroll
  for (int rt = 0; rt < 2; rt++) {
    accw[rt] = (f32x4){0.f, 0.f, 0.f, 0.f};
#pragma unroll
    for (int ct = 0; ct < 8; ct++) acc1[rt][ct] = (f32x4){0.f, 0.f, 0.f, 0.f};
  }

#pragma unroll
  for (int ks = 0; ks < 4; ks++) {
    frag_u a[2];
#pragma unroll
    for (int rt = 0; rt < 2; rt++) {
      const float* p = xrow[rt] + ks * 32 + q * 8;
      float4 v0 = *(const float4*)p;
      float4 v1 = *(const float4*)(p + 4);
      a[rt].s = (s16x8){(short)f2b(v0.x), (short)f2b(v0.y), (short)f2b(v0.z), (short)f2b(v0.w),
                        (short)f2b(v1.x), (short)f2b(v1.y), (short)f2b(v1.z), (short)f2b(v1.w)};
    }
    frag_u bw;
    bw.s = *(const s16x8*)(Wsh + m * 136 + ks * 32 + q * 8);
#pragma unroll
    for (int rt = 0; rt < 2; rt++)
      accw[rt] = __builtin_amdgcn_mfma_f32_16x16x32_bf16(a[rt].b, bw.b, accw[rt], 0, 0, 0);
#pragma unroll
    for (int ct = 0; ct < 8; ct++) {
      frag_u b1;
      b1.s = *(const s16x8*)(Bs1 + (ct * 16 + m) * 136 + ks * 32 + q * 8);
#pragma unroll
      for (int rt = 0; rt < 2; rt++)
        acc1[rt][ct] = __builtin_amdgcn_mfma_f32_16x16x32_bf16(a[rt].b, b1.b, acc1[rt][ct], 0, 0, 0);
    }
  }

#pragma unroll
  for (int rt = 0; rt < 2; rt++) {
#pragma unroll
    for (int i = 0; i < 4; i++) {
      int r = m0 + (wave * 2 + rt) * 16 + q * 4 + i;
      if (r < M) {
        unsigned short* xr = xs_out + (size_t)r * 128 + m;
#pragma unroll
        for (int ct = 0; ct < 8; ct++) xr[ct * 16] = f2b(acc1[rt][ct][i]);
        if (m < 4) as_out[(size_t)r * 4 + m] = accw[rt][i];
      }
    }
  }
}

// ================= gathers =================

// GAT gather, bf16 payload, unroll x2; out = xd + s*bias + s*softmax-weighted-mean
__global__ __launch_bounds__(256) void gat_gather(const int* __restrict__ rowptr,
                                                  const int* __restrict__ col,
                                                  const float* __restrict__ a_s,
                                                  const float* __restrict__ a_d,
                                                  const unsigned short* __restrict__ xs,
                                                  const float* __restrict__ xd_in,
                                                  const float* __restrict__ bias,
                                                  float* __restrict__ out, int Nd, float s) {
  int node = blockIdx.x * 8 + (threadIdx.x >> 5);
  if (node >= Nd) return;
  int g = threadIdx.x & 31;
  int c4 = g * 4, h = g >> 3;
  int lo = rowptr[node], hi = rowptr[node + 1];
  float ad = a_d[(size_t)node * 4 + h];
  float4 acc = {0.f, 0.f, 0.f, 0.f};
  float sexp = 0.f;
  int j = lo;
  for (; j + 1 < hi; j += 2) {
    int s0 = col[j], s1 = col[j + 1];
    float l0 = a_s[(size_t)s0 * 4 + h] + ad;
    float l1 = a_s[(size_t)s1 * 4 + h] + ad;
    ushort4 u0 = *(const ushort4*)(xs + (size_t)s0 * 128 + c4);
    ushort4 u1 = *(const ushort4*)(xs + (size_t)s1 * 128 + c4);
    l0 = l0 > 0.f ? l0 : 0.2f * l0;
    l1 = l1 > 0.f ? l1 : 0.2f * l1;
    float w0 = __expf(l0), w1 = __expf(l1);
    sexp += w0 + w1;
    acc.x += w0 * b2f(u0.x) + w1 * b2f(u1.x);
    acc.y += w0 * b2f(u0.y) + w1 * b2f(u1.y);
    acc.z += w0 * b2f(u0.z) + w1 * b2f(u1.z);
    acc.w += w0 * b2f(u0.w) + w1 * b2f(u1.w);
  }
  if (j < hi) {
    int s0 = col[j];
    float l0 = a_s[(size_t)s0 * 4 + h] + ad;
    ushort4 u0 = *(const ushort4*)(xs + (size_t)s0 * 128 + c4);
    l0 = l0 > 0.f ? l0 : 0.2f * l0;
    float w0 = __expf(l0);
    sexp += w0;
    acc.x += w0 * b2f(u0.x);
    acc.y += w0 * b2f(u0.y);
    acc.z += w0 * b2f(u0.z);
    acc.w += w0 * b2f(u0.w);
  }
  float inv = s / (sexp + 1e-16f);
  float4 xd = *(const float4*)(xd_in + (size_t)node * 128 + c4);
  float4 bv = *(const float4*)(bias + c4);
  float4 r = {xd.x + s * bv.x + inv * acc.x, xd.y + s * bv.y + inv * acc.y,
              xd.z + s * bv.z + inv * acc.z, xd.w + s * bv.w + inv * acc.w};
  *(float4*)(out + (size_t)node * 128 + c4) = r;
}

// GCN gather: hgs rows are pre-scaled by dinv[src]; self row folded into the sum.
// out = x + s*(dinv[node]*(sum_rows) + bias)
__global__ __launch_bounds__(256) void gcn_gather(const int* __restrict__ rowptr,
                                                  const int* __restrict__ col,
                                                  const unsigned short* __restrict__ hgs,
                                                  const float* __restrict__ dinv,
                                                  const float* __restrict__ x,
                                                  const float* __restrict__ bias,
                                                  float* __restrict__ out, int N, float s) {
  int node = blockIdx.x * 8 + (threadIdx.x >> 5);
  if (node >= N) return;
  int c4 = (threadIdx.x & 31) * 4;
  int lo = rowptr[node], hi = rowptr[node + 1];
  // self row (pre-scaled by dinv[node])
  ushort4 su = *(const ushort4*)(hgs + (size_t)node * 128 + c4);
  float4 acc = {b2f(su.x), b2f(su.y), b2f(su.z), b2f(su.w)};
  int j = lo;
  for (; j + 1 < hi; j += 2) {
    int s0 = col[j], s1 = col[j + 1];
    ushort4 u0 = *(const ushort4*)(hgs + (size_t)s0 * 128 + c4);
    ushort4 u1 = *(const ushort4*)(hgs + (size_t)s1 * 128 + c4);
    acc.x += b2f(u0.x) + b2f(u1.x);
    acc.y += b2f(u0.y) + b2f(u1.y);
    acc.z += b2f(u0.z) + b2f(u1.z);
    acc.w += b2f(u0.w) + b2f(u1.w);
  }
  if (j < hi) {
    int s0 = col[j];
    ushort4 u0 = *(const ushort4*)(hgs + (size_t)s0 * 128 + c4);
    acc.x += b2f(u0.x); acc.y += b2f(u0.y); acc.z += b2f(u0.z); acc.w += b2f(u0.w);
  }
  float dd = dinv[node];
  float4 xv = *(const float4*)(x + (size_t)node * 128 + c4);
  float4 bv = *(const float4*)(bias + c4);
  float4 r = {xv.x + s * (dd * acc.x + bv.x), xv.y + s * (dd * acc.y + bv.y),
              xv.z + s * (dd * acc.z + bv.z), xv.w + s * (dd * acc.w + bv.w)};
  *(float4*)(out + (size_t)node * 128 + c4) = r;
}

// ================= host =================
extern "C" void kernel_launch(void* const* d_in, const int* in_sizes, int n_in,
                              void* d_out, int out_size, void* d_ws, size_t ws_size,
                              hipStream_t stream) {
  const float* x_b        = (const float*)d_in[0];
  const float* x_c        = (const float*)d_in[1];
  const float* x_t        = (const float*)d_in[2];
  const int*   e_b2c      = (const int*)d_in[3];
  const int*   e_c2t      = (const int*)d_in[4];
  const int*   e_adj      = (const int*)d_in[5];
  const float* W_b2c_src  = (const float*)d_in[6];
  const float* W_b2c_dst  = (const float*)d_in[7];
  const float* att_b2c_s  = (const float*)d_in[8];
  const float* att_b2c_d  = (const float*)d_in[9];
  const float* b_b2c      = (const float*)d_in[10];
  const float* W_c2t_src  = (const float*)d_in[11];
  const float* W_c2t_dst  = (const float*)d_in[12];
  const float* att_c2t_s  = (const float*)d_in[13];
  const float* att_c2t_d  = (const float*)d_in[14];
  const float* b_c2t      = (const float*)d_in[15];
  const float* W_gcn      = (const float*)d_in[16];
  const float* b_gcn      = (const float*)d_in[17];

  float* h_b = (float*)d_out;
  float* h_c = h_b + (size_t)NB * 128;
  float* h_t = h_c + (size_t)NC * 128;

  char* w = (char*)d_ws;
  auto allocu = [&](size_t n) { unsigned short* p = (unsigned short*)w; w += n * 2; return p; };
  auto allocf = [&](size_t n) { float* p = (float*)w; w += n * 4; return p; };
  auto alloci = [&](size_t n) { int* p = (int*)w; w += n * 4; return p; };

  // 16B-aligned-sensitive arrays first
  unsigned short* xs_b = allocu((size_t)NB * 128);   // bf16 payloads
  unsigned short* hgs  = allocu((size_t)NB * 128);   // bf16, pre-scaled by dinv
  unsigned short* xs_c = allocu((size_t)NC * 128);
  float* a_d_c = allocf((size_t)NC * 4);
  float* a_d_t = allocf((size_t)NT * 4);
  float* a_s_b = allocf((size_t)NB * 4);
  float* a_s_c = allocf((size_t)NC * 4);
  float* dinv  = allocf(NB);
  float* wt    = allocf(4 * 512);
  int* deg_a = alloci(NB);   // deg_a..deg_c contiguous for one memset
  int* deg_b = alloci(NC);
  int* deg_c = alloci(NT);
  int* bs    = alloci(64);
  int* rp_a  = alloci(NB + 1);  int* cur_a = alloci(NB);  int* col_a = alloci(EADJ);
  int* rp_b  = alloci(NC + 1);  int* cur_b = alloci(NC);  int* col_b = alloci(EB2C);
  int* rp_c  = alloci(NT + 1);  int* cur_c = alloci(NT);  int* col_c = alloci(EC2T);

  const int ETOT = EADJ + EB2C + EC2T;

  // ---- CSR build (merged) ----
  hipMemsetAsync(deg_a, 0, (size_t)(NB + NC + NT) * sizeof(int), stream);
  deg_count_all<<<(ETOT + 255) / 256, 256, 0, stream>>>(e_adj, e_b2c, e_c2t, deg_a, deg_b, deg_c);
  scan_bsum_all<<<SBA + SBB + SBC, 256, 0, stream>>>(deg_a, deg_b, deg_c, bs);
  scan_excl_all<<<3, 256, 0, stream>>>(bs);
  scan_write_all<<<SBA + SBB + SBC, 256, 0, stream>>>(deg_a, deg_b, deg_c, bs,
                                                      rp_a, cur_a, rp_b, cur_b, rp_c, cur_c, dinv);
  csr_fill_all<<<(ETOT + 255) / 256, 256, 0, stream>>>(e_adj, e_b2c, e_c2t,
                                                       cur_a, cur_b, cur_c, col_a, col_b, col_c);

  // ---- attention-weight folding + dst logits ----
  prep_watt<<<1, 256, 0, stream>>>(W_b2c_src, att_b2c_s, W_b2c_dst, att_b2c_d,
                                   W_c2t_src, att_c2t_s, W_c2t_dst, att_c2t_d, wt);
  small_ad<<<(NC + NT + 3) / 4, 256, 0, stream>>>(x_c, x_t, wt, a_d_c, a_d_t);

  // ---- big fused GEMM: x_b -> xs_b (bf16), hgs (bf16, dinv-scaled), a_s_b ----
  gemm_dual<<<(NB + 127) / 128, 256, 0, stream>>>(x_b, W_b2c_src, W_gcn, wt, dinv,
                                                  xs_b, hgs, a_s_b, NB);

  // ---- stage A: building -> cable_group GAT ----
  gat_gather<<<(NC + 7) / 8, 256, 0, stream>>>(rp_b, col_b, a_s_b, a_d_c,
                                               xs_b, x_c, b_b2c, h_c, NC, 0.5f);

  // ---- stage B: cable_group -> transformer GAT ----
  gemm_single<<<(NC + 127) / 128, 256, 0, stream>>>(h_c, W_c2t_src, wt + 1024, xs_c, a_s_c, NC);
  gat_gather<<<(NT + 7) / 8, 256, 0, stream>>>(rp_c, col_c, a_s_c, a_d_t,
                                               xs_c, x_t, b_c2t, h_t, NT, 0.5f);

  // ---- GCN on building adjacency ----
  gcn_gather<<<(NB + 7) / 8, 256, 0, stream>>>(rp_a, col_a, hgs, dinv, x_b, b_gcn, h_b, NB, 0.2f);
}